// Round 12
// baseline (475.803 us; speedup 1.0000x reference)
//
#include <hip/hip_runtime.h>
#include <hip/hip_bf16.h>
#include <stdint.h>

typedef float f32x4_t __attribute__((ext_vector_type(4)));
typedef short s16x8_t __attribute__((ext_vector_type(8)));

#define LDS_AS __attribute__((address_space(3)))
#define GLB_AS __attribute__((address_space(1)))

__device__ __forceinline__ void gload16(void* lds, const void* g) {
    __builtin_amdgcn_global_load_lds((const GLB_AS uint32_t*)g,
                                     (LDS_AS uint32_t*)lds, 16, 0, 0);
}

__device__ __forceinline__ uint32_t pack_bf16(float lo, float hi) {
    union { __hip_bfloat16 h; uint16_t u; } a, b;
    a.h = __float2bfloat16(lo); b.h = __float2bfloat16(hi);
    return (uint32_t)a.u | ((uint32_t)b.u << 16);
}

// ---------------- RoPE table: cos/sin[s][j], j in [0,64), invf index j&31 ----------------
__global__ __launch_bounds__(256) void rope_table_kernel(float* __restrict__ cos_t,
                                                         float* __restrict__ sin_t) {
    int idx = blockIdx.x * 256 + threadIdx.x;       // 1024*64 exact
    int s = idx >> 6, j = idx & 63;
    float invf = powf(10000.0f, -((float)((j & 31) * 2)) / 64.0f);
    float a = (float)s * invf;
    cos_t[idx] = cosf(a);
    sin_t[idx] = sinf(a);
}

// ---------------- fp32 -> bf16 convert (x4 vectorized) ----------------
__global__ __launch_bounds__(256) void f32_to_bf16_kernel(const float* __restrict__ in,
                                                          __hip_bfloat16* __restrict__ out, int n4) {
    int i = blockIdx.x * 256 + threadIdx.x;
    if (i >= n4) return;
    float4 v = reinterpret_cast<const float4*>(in)[i];
    struct __align__(8) BF4 { __hip_bfloat16 a, b, c, d; } r;
    r.a = __float2bfloat16(v.x); r.b = __float2bfloat16(v.y);
    r.c = __float2bfloat16(v.z); r.d = __float2bfloat16(v.w);
    reinterpret_cast<BF4*>(out)[i] = r;
}

// ------- transpose + convert + scale (vectorized): W[K][N] f32 -> WT[Npad][K] bf16 -------
__global__ __launch_bounds__(256) void transpose_convert(const float* __restrict__ W,
                                                         __hip_bfloat16* __restrict__ WT,
                                                         int K, int N, int Npad, float scale) {
    __shared__ float tile[32][132];
    int k0 = blockIdx.y * 32, n0 = blockIdx.x * 128;
    int tx = threadIdx.x & 31, ty = threadIdx.x >> 5;   // tx: n-quad, ty: k-row
#pragma unroll
    for (int i = 0; i < 4; i++) {
        int ky = i * 8 + ty;
        int n = n0 + tx * 4;
        float4 v;
        if (n + 3 < N) {
            v = *(const float4*)&W[(size_t)(k0 + ky) * N + n];
        } else {
            float t0 = (n + 0 < N) ? W[(size_t)(k0 + ky) * N + n + 0] : 0.f;
            float t1 = (n + 1 < N) ? W[(size_t)(k0 + ky) * N + n + 1] : 0.f;
            float t2 = (n + 2 < N) ? W[(size_t)(k0 + ky) * N + n + 2] : 0.f;
            float t3 = (n + 3 < N) ? W[(size_t)(k0 + ky) * N + n + 3] : 0.f;
            v = make_float4(t0, t1, t2, t3);
        }
        *(float4*)&tile[ky][tx * 4] = v;
    }
    __syncthreads();
    int ny = threadIdx.x & 127, kh = threadIdx.x >> 7;   // ny 0..127, kh 0..1
#pragma unroll
    for (int oct = 0; oct < 2; oct++) {
        int kb = kh * 16 + oct * 8;
        union { short s[8]; s16x8_t v; } pk;
#pragma unroll
        for (int e = 0; e < 8; e++) {
            union { __hip_bfloat16 h; short s; } cv;
            cv.h = __float2bfloat16(tile[kb + e][ny] * scale);
            pk.s[e] = cv.s;
        }
        *(s16x8_t*)&WT[(size_t)(n0 + ny) * K + k0 + kb] = pk.v;
    }
}

// ---------------- rmsnorm: in f32 [2048][in_stride] (cols used) -> out bf16 [2048][cols] ----
__global__ __launch_bounds__(256) void rmsnorm_kernel(const float* __restrict__ in,
                                                      const float* __restrict__ g,
                                                      __hip_bfloat16* __restrict__ out,
                                                      int cols, int in_stride) {
    int row = blockIdx.x;
    const float* x = in + (size_t)row * in_stride;
    float ss = 0.f;
    for (int c = threadIdx.x; c < cols; c += 256) { float v = x[c]; ss += v * v; }
#pragma unroll
    for (int off = 32; off > 0; off >>= 1) ss += __shfl_xor(ss, off);
    __shared__ float red[4];
    if ((threadIdx.x & 63) == 0) red[threadIdx.x >> 6] = ss;
    __syncthreads();
    float tot = red[0] + red[1] + red[2] + red[3];
    float rms = sqrtf(tot / (float)cols);
    float inv = 1.0f / (rms + 1e-6f);
    for (int c = threadIdx.x; c < cols; c += 256)
        out[(size_t)row * cols + c] = __float2bfloat16(x[c] * inv * g[c]);
}

// ---------------- k_rope: kv[tok][512..575] f32 -> roped bf16 [tok][64] (no scale) --------
__global__ __launch_bounds__(256) void rope_k_kernel(const float* __restrict__ kv,
                                                     const float* __restrict__ cos_t,
                                                     const float* __restrict__ sin_t,
                                                     __hip_bfloat16* __restrict__ k_rope) {
    int idx = blockIdx.x * 256 + threadIdx.x;       // 2048*32 exact
    int tok = idx >> 5, j = idx & 31;
    int s = tok & 1023;
    const float* x = kv + (size_t)tok * 640 + 512;
    float x1 = x[j], x2 = x[j + 32];
    float co = cos_t[s * 64 + j], si = sin_t[s * 64 + j];
    __hip_bfloat16* o = k_rope + (size_t)tok * 64;
    o[j]      = __float2bfloat16(x1 * co - x2 * si);
    o[j + 32] = __float2bfloat16(x2 * co + x1 * si);
}

// ---------------- q rope (scale already folded into w_qb): rotate cols h*192+128..191 -----
__global__ __launch_bounds__(256) void rope_q_kernel(__hip_bfloat16* __restrict__ q,
                                                     const float* __restrict__ cos_t,
                                                     const float* __restrict__ sin_t) {
    int tok = blockIdx.x;
    int s = tok & 1023;
    __hip_bfloat16* row = q + (size_t)tok * 6144;
#pragma unroll
    for (int it = 0; it < 4; it++) {                  // 32 heads x 32 pairs
        int i = it * 256 + threadIdx.x;
        int h = i >> 5, j = i & 31;
        int c = h * 192 + 128 + j;
        float x1 = __bfloat162float(row[c]), x2 = __bfloat162float(row[c + 32]);
        float co = cos_t[s * 64 + j], si = sin_t[s * 64 + j];
        row[c]      = __float2bfloat16(x1 * co - x2 * si);
        row[c + 32] = __float2bfloat16(x2 * co + x1 * si);
    }
}

// ---------------- V transpose: kst[tok][h*256+128..255] -> V_T[bh][vd][1024] -------------
__global__ __launch_bounds__(256) void transpose_v_kernel(const __hip_bfloat16* __restrict__ kst,
                                                          __hip_bfloat16* __restrict__ V_T) {
    __shared__ __hip_bfloat16 t[64][136];
    int bid = blockIdx.x;                 // (b*32+h)*16 + st
    int st = bid & 15, bh = bid >> 4;
    int h = bh & 31, b = bh >> 5;
    int s0 = st * 64;
#pragma unroll
    for (int i = 0; i < 4; i++) {
        int c = i * 256 + threadIdx.x;    // 64 rows x 16 octs
        int r = c >> 4, oct = c & 15;
        *(s16x8_t*)&t[r][oct * 8] =
            *(const s16x8_t*)&kst[(size_t)(b * 1024 + s0 + r) * 8192 + h * 256 + 128 + oct * 8];
    }
    __syncthreads();
#pragma unroll
    for (int i = 0; i < 4; i++) {
        int c = i * 256 + threadIdx.x;    // 128 vd x 8 octs
        int vd = c >> 3, oct = c & 7;
        s16x8_t pk;
#pragma unroll
        for (int e = 0; e < 8; e++) pk[e] = *(const short*)&t[oct * 8 + e][vd];
        *(s16x8_t*)&V_T[((size_t)bh * 128 + vd) * 1024 + s0 + oct * 8] = pk;
    }
}

// ---------------- GEMM: A[M][K] bf16 x BT[N][K] bf16 -> C -------------
// MODE 0: f32 C[M][N]. MODE 1: bf16 C[M][N]. MODE 2: split f32.
template <int MODE>
__global__ __launch_bounds__(256, 3) void gemm_bt_128(const __hip_bfloat16* __restrict__ A,
                                                      const __hip_bfloat16* __restrict__ BT,
                                                      void* __restrict__ Cout, void* __restrict__ C1,
                                                      int M, int N, int K, int N0, int N1) {
    __shared__ __hip_bfloat16 As[128 * 64];
    __shared__ __hip_bfloat16 Bs[128 * 64];
    const int tid = threadIdx.x;
    const int l = tid & 63, w = tid >> 6;
    const int wr = w >> 1, wc = w & 1;
    const int m0 = blockIdx.y * 128, n0 = blockIdx.x * 128;
    const int lrow = l & 15, lkg = l >> 4;

    f32x4_t acc[4][4];
#pragma unroll
    for (int i = 0; i < 4; i++)
#pragma unroll
        for (int j = 0; j < 4; j++) acc[i][j] = (f32x4_t){0.f, 0.f, 0.f, 0.f};

    for (int k0 = 0; k0 < K; k0 += 64) {
        __syncthreads();
#pragma unroll
        for (int i = 0; i < 4; i++) {
            int s = i * 256 + tid;          // 1024 16B slots per tile
            int row = s >> 3, po = s & 7;
            int lo = po ^ (row & 7);        // logical k-octet for this physical slot
            gload16(&As[s * 8], &A[(size_t)(m0 + row) * K + k0 + lo * 8]);
            gload16(&Bs[s * 8], &BT[(size_t)(n0 + row) * K + k0 + lo * 8]);
        }
        __syncthreads();
#pragma unroll
        for (int ks = 0; ks < 2; ks++) {
            s16x8_t a[4], b[4];
#pragma unroll
            for (int m = 0; m < 4; m++) {
                int row = wr * 64 + m * 16 + lrow;
                int oct = (ks * 4 + lkg) ^ (row & 7);
                a[m] = *(const s16x8_t*)&As[row * 64 + oct * 8];
            }
#pragma unroll
            for (int n = 0; n < 4; n++) {
                int row = wc * 64 + n * 16 + lrow;
                int oct = (ks * 4 + lkg) ^ (row & 7);
                b[n] = *(const s16x8_t*)&Bs[row * 64 + oct * 8];
            }
#pragma unroll
            for (int m = 0; m < 4; m++)
#pragma unroll
                for (int n = 0; n < 4; n++)
                    acc[m][n] = __builtin_amdgcn_mfma_f32_16x16x32_bf16(a[m], b[n], acc[m][n], 0, 0, 0);
        }
    }
#pragma unroll
    for (int m = 0; m < 4; m++) {
        int row = m0 + wr * 64 + m * 16 + lkg * 4;
#pragma unroll
        for (int n = 0; n < 4; n++) {
            int col = n0 + wc * 64 + n * 16 + lrow;
#pragma unroll
            for (int r = 0; r < 4; r++) {
                float v = acc[m][n][r];
                if (MODE == 1) {
                    ((__hip_bfloat16*)Cout)[(size_t)(row + r) * N + col] = __float2bfloat16(v);
                } else if (MODE == 0) {
                    ((float*)Cout)[(size_t)(row + r) * N + col] = v;
                } else {
                    if (col < N0) ((float*)Cout)[(size_t)(row + r) * N0 + col] = v;
                    else          ((float*)C1)[(size_t)(row + r) * N1 + (col - N0)] = v;
                }
            }
        }
    }
}

// ------- attention v12: attn8 logic x 8 waves (QBLK=128), launch_bounds(512,2) -----------
// Block = 128 q rows of one (b,h); 8 waves x 16 rows; KV tiles of 64, 16 iters; grid 512
// = exactly 2 blocks/CU x 256 CU (one full round, zero tail, 16 waves/CU).
// launch_bounds(512,2): reg cap 256 >> ~150 demand -> NO spill (R3-R10 law: 128-cap
// always spills for this kernel; (512,4) was the R3/R4 disaster, (512,2) is safe).
// K-stage amortized 2x vs attn8 (one 64x192 tile serves 128 q-rows). Per-wave logic
// byte-identical to validated attn8: swapped QK^T (mfma(K,Q)) -> lane-private softmax,
// P via shfl (no P-LDS), PV = mfma(V^T,P^T) -> O^T, epilogue LDS-bounce transpose.
__global__ __launch_bounds__(512, 2) void attn12_kernel(const __hip_bfloat16* __restrict__ q,
                                                        const __hip_bfloat16* __restrict__ kst,
                                                        const __hip_bfloat16* __restrict__ k_rope,
                                                        const __hip_bfloat16* __restrict__ V_T,
                                                        __hip_bfloat16* __restrict__ attn_out) {
    __shared__ __align__(16) __hip_bfloat16 Ks[2][64 * 192];  // 48 KB total

    // XCD-bijective swizzle: the 8 q-tiles of one (b,h) land on the same XCD (i%8 const).
    int i = blockIdx.x;                       // grid 512
    int bh = (i & 7) * 8 + ((i >> 3) & 7);
    int qt = i >> 6;                          // [0,8)
    int h = bh & 31, b = bh >> 5;
    int q0 = qt * 128;
    int tid = threadIdx.x, l = tid & 63, w = tid >> 6;   // w in [0,8)
    int lrow = l & 15, lkg = l >> 4;

    // Q fragments (B-operand): lane lrow <-> q-row q0+w*16+lrow, lkg <-> k-chunk
    s16x8_t qa[6];
    {
        size_t qbase = (size_t)(b * 1024 + q0 + w * 16 + lrow) * 6144 + h * 192;
#pragma unroll
        for (int f = 0; f < 6; f++)
            qa[f] = *(const s16x8_t*)&q[qbase + f * 32 + lkg * 8];
    }
    // acc_o[n][r] = O^T[vd = n*16 + lkg*4 + r][q = lrow]
    f32x4_t acc_o[8];
#pragma unroll
    for (int n = 0; n < 8; n++) acc_o[n] = (f32x4_t){0.f, 0.f, 0.f, 0.f};
    float m_run = -1e30f, l_run = 0.f;        // lane-private (one q-row per lane)

    size_t krow_base = (size_t)(b * 1024) * 8192 + h * 256;
    size_t rrow_base = (size_t)(b * 1024) * 64;
    const __hip_bfloat16* vbase = V_T + (size_t)bh * 128 * 1024 + (size_t)lrow * 1024 + lkg * 8;

    // stage K tile kv0 -> Ks[buf]: 64 rows x 24 slots (16 nope + 8 rope), linear LDS dest,
    // inverse-swizzled global source (lo = po ^ (row&7), closed within 8-slot groups).
    auto stage_k = [&](int kv0, int buf) {
#pragma unroll
        for (int it = 0; it < 3; it++) {
            int s = it * 512 + tid;               // 0..1535
            int row = s / 24, po = s - row * 24;
            int lo = po ^ (row & 7);
            const __hip_bfloat16* src = (lo < 16)
                ? &kst[krow_base + (size_t)(kv0 + row) * 8192 + lo * 8]
                : &k_rope[rrow_base + (size_t)(kv0 + row) * 64 + (lo - 16) * 8];
            gload16(&Ks[buf][s * 8], src);
        }
    };

    stage_k(0, 0);
    asm volatile("s_waitcnt vmcnt(0)" ::: "memory");
    __syncthreads();

    const int src0 = lrow + ((lkg & 1) << 5);   // P^T-frag shuffle sources
    const int src1 = src0 + 16;
    const bool hiC = (lkg >> 1) != 0;           // needs c = 2kk+1 variant

    int cur = 0;
    for (int kt = 0; kt < 16; kt++) {
        int kv0 = kt * 64;

        // ---- stage next tile at TOP (hides under QK^T + softmax) ----
        if (kt < 15) stage_k(kv0 + 64, cur ^ 1);

        // ---- QK^T SWAPPED: sc[c][r] = S[kv0 + c*16 + lkg*4 + r][q-row lrow] ----
        f32x4_t sc[4];
#pragma unroll
        for (int c = 0; c < 4; c++) sc[c] = (f32x4_t){0.f, 0.f, 0.f, 0.f};
        __builtin_amdgcn_s_setprio(1);
#pragma unroll
        for (int c = 0; c < 4; c++) {
            int row = c * 16 + lrow;
#pragma unroll
            for (int f = 0; f < 6; f++) {
                int po = ((f * 4 + lkg) ^ (lrow & 7)) * 8;
                s16x8_t kb = *(const s16x8_t*)&Ks[cur][row * 192 + po];
                sc[c] = __builtin_amdgcn_mfma_f32_16x16x32_bf16(kb, qa[f], sc[c], 0, 0, 0);
            }
        }
        __builtin_amdgcn_s_setprio(0);

        // ---- V half 0 loads (L2 latency hides under softmax) ----
        s16x8_t vb0[8];
#pragma unroll
        for (int n = 0; n < 8; n++)
            vb0[n] = *(const s16x8_t*)&vbase[(size_t)(n * 16) * 1024 + kv0];
        __builtin_amdgcn_sched_barrier(0);

        // ---- lane-private online softmax (q-row lrow), T13 defer-max ----
        float mx = sc[0][0];
#pragma unroll
        for (int c = 0; c < 4; c++)
#pragma unroll
            for (int r = 0; r < 4; r++) mx = fmaxf(mx, sc[c][r]);
        mx = fmaxf(mx, __shfl_xor(mx, 16));
        mx = fmaxf(mx, __shfl_xor(mx, 32));
        if (!__all(mx - m_run <= 8.0f)) {
            float mn = fmaxf(m_run, mx);
            float al = __expf(m_run - mn);
            m_run = mn;
            l_run *= al;
#pragma unroll
            for (int n = 0; n < 8; n++) acc_o[n] *= al;
        }
        uint32_t u[4][2];
        float sum = 0.f;
#pragma unroll
        for (int c = 0; c < 4; c++) {
            float p0 = __expf(sc[c][0] - m_run), p1 = __expf(sc[c][1] - m_run);
            float p2 = __expf(sc[c][2] - m_run), p3 = __expf(sc[c][3] - m_run);
            sum += (p0 + p1) + (p2 + p3);
            u[c][0] = pack_bf16(p0, p1);
            u[c][1] = pack_bf16(p2, p3);
        }
        sum += __shfl_xor(sum, 16);
        sum += __shfl_xor(sum, 32);
        l_run += sum;

        // ---- PV half 0: assemble P^T frag (kv 0..31) via shfl, mfma(V^T, P^T) ----
        {
            uint32_t a0 = __shfl((int)u[0][0], src0), b0 = __shfl((int)u[1][0], src0);
            uint32_t a1 = __shfl((int)u[0][1], src0), b1 = __shfl((int)u[1][1], src0);
            uint32_t a2 = __shfl((int)u[0][0], src1), b2 = __shfl((int)u[1][0], src1);
            uint32_t a3 = __shfl((int)u[0][1], src1), b3 = __shfl((int)u[1][1], src1);
            union { uint32_t wd[4]; s16x8_t v; } pb;
            pb.wd[0] = hiC ? b0 : a0;
            pb.wd[1] = hiC ? b1 : a1;
            pb.wd[2] = hiC ? b2 : a2;
            pb.wd[3] = hiC ? b3 : a3;
            __builtin_amdgcn_s_setprio(1);
#pragma unroll
            for (int n = 0; n < 8; n++)
                acc_o[n] = __builtin_amdgcn_mfma_f32_16x16x32_bf16(vb0[n], pb.v, acc_o[n], 0, 0, 0);
            __builtin_amdgcn_s_setprio(0);
        }
        // ---- V half 1 loads, then PV half 1 (kv 32..63) ----
        s16x8_t vb1[8];
#pragma unroll
        for (int n = 0; n < 8; n++)
            vb1[n] = *(const s16x8_t*)&vbase[(size_t)(n * 16) * 1024 + kv0 + 32];
        {
            uint32_t a0 = __shfl((int)u[2][0], src0), b0 = __shfl((int)u[3][0], src0);
            uint32_t a1 = __shfl((int)u[2][1], src0), b1 = __shfl((int)u[3][1], src0);
            uint32_t a2 = __shfl((int)u[2][0], src1), b2 = __shfl((int)u[3][0], src1);
            uint32_t a3 = __shfl((int)u[2][1], src1), b3 = __shfl((int)u[3][1], src1);
            union { uint32_t wd[4]; s16x8_t v; } pb;
            pb.wd[0] = hiC ? b0 : a0;
            pb.wd[1] = hiC ? b1 : a1;
            pb.wd[2] = hiC ? b2 : a2;
            pb.wd[3] = hiC ? b3 : a3;
            __builtin_amdgcn_s_setprio(1);
#pragma unroll
            for (int n = 0; n < 8; n++)
                acc_o[n] = __builtin_amdgcn_mfma_f32_16x16x32_bf16(vb1[n], pb.v, acc_o[n], 0, 0, 0);
            __builtin_amdgcn_s_setprio(0);
        }

        asm volatile("s_waitcnt vmcnt(0)" ::: "memory");
        __syncthreads();
        cur ^= 1;
    }

    // ---- epilogue: O^T -> O via per-wave LDS bounce in dead Ks space (8x4352B = 34KB) ----
    float inv = 1.0f / l_run;
    __hip_bfloat16* Ob = &Ks[0][0] + (size_t)w * (16 * 136);   // 16 rows x 136 (pad)
#pragma unroll
    for (int n = 0; n < 8; n++) {
        uint32_t lo = pack_bf16(acc_o[n][0] * inv, acc_o[n][1] * inv);
        uint32_t hi = pack_bf16(acc_o[n][2] * inv, acc_o[n][3] * inv);
        uint32_t* dst = (uint32_t*)&Ob[lrow * 136 + n * 16 + lkg * 4];
        dst[0] = lo;
        dst[1] = hi;
    }
    asm volatile("s_waitcnt lgkmcnt(0)" ::: "memory");
    __builtin_amdgcn_sched_barrier(0);
#pragma unroll
    for (int it = 0; it < 4; it++) {
        int tr = it * 4 + lkg;
        s16x8_t ov = *(const s16x8_t*)&Ob[tr * 136 + lrow * 8];
        *(s16x8_t*)&attn_out[(size_t)(b * 1024 + q0 + w * 16 + tr) * 4096 + h * 128 + lrow * 8] = ov;
    }
}

extern "C" void kernel_launch(void* const* d_in, const int* in_sizes, int n_in,
                              void* d_out, int out_size, void* d_ws, size_t ws_size,
                              hipStream_t stream) {
    const float* hidden = (const float*)d_in[0];
    const float* w_qa   = (const float*)d_in[1];
    const float* g_qa   = (const float*)d_in[2];
    const float* w_qb   = (const float*)d_in[3];
    const float* w_kva  = (const float*)d_in[4];
    const float* g_kva  = (const float*)d_in[5];
    const float* w_kvb  = (const float*)d_in[6];
    const float* w_o    = (const float*)d_in[7];
    float* out = (float*)d_out;

    char* base = (char*)d_ws;
    size_t off = 0;
    auto alloc = [&](size_t bytes) -> void* {
        off = (off + 255) & ~(size_t)255;
        void* p = base + off;
        off += bytes;
        return p;
    };
    float* cos_t = (float*)alloc(1024 * 64 * 4);
    float* sin_t = (float*)alloc(1024 * 64 * 4);
    __hip_bfloat16* hid_b  = (__hip_bfloat16*)alloc(2048ull * 4096 * 2);  // later reused as V_T
    // wqaT and wkvaT MUST be adjacent+contiguous: combined BT [2176][4096] for merged GEMM.
    __hip_bfloat16* wqaT   = (__hip_bfloat16*)alloc(1536ull * 4096 * 2);  // 12582912 B, 256-aligned
    __hip_bfloat16* wkvaT  = (__hip_bfloat16*)alloc(640ull * 4096 * 2);   // = wqaT + 1536*4096
    __hip_bfloat16* wqbT   = (__hip_bfloat16*)alloc(6144ull * 1536 * 2);  // later reused as attn_out
    __hip_bfloat16* wkvbT  = (__hip_bfloat16*)alloc(8192ull * 512 * 2);
    __hip_bfloat16* woT    = (__hip_bfloat16*)alloc(4096ull * 4096 * 2);
    float* q_a             = (float*)alloc(2048ull * 1536 * 4);
    __hip_bfloat16* q_c    = (__hip_bfloat16*)alloc(2048ull * 1536 * 2);
    __hip_bfloat16* q_buf  = (__hip_bfloat16*)alloc(2048ull * 6144 * 2);
    float* kv              = (float*)alloc(2048ull * 640 * 4);
    __hip_bfloat16* k_c    = (__hip_bfloat16*)alloc(2048ull * 512 * 2);
    __hip_bfloat16* k_rope = (__hip_bfloat16*)alloc(2048ull * 64 * 2);
    __hip_bfloat16* kst    = (__hip_bfloat16*)alloc(2048ull * 8192 * 2);
    __hip_bfloat16* V_T      = hid_b;   // hid_b dead after the merged first GEMM
    __hip_bfloat16* attn_out = wqbT;    // wqbT dead after q GEMM

    const float qscale = 0.07216878364870323f;   // 192^-0.5, folded into w_qb

    rope_table_kernel<<<256, 256, 0, stream>>>(cos_t, sin_t);
    f32_to_bf16_kernel<<<8192, 256, 0, stream>>>(hidden, hid_b, 2048 * 4096 / 4);
    transpose_convert<<<dim3(1536 / 128, 4096 / 32), 256, 0, stream>>>(w_qa, wqaT, 4096, 1536, 1536, 1.0f);
    transpose_convert<<<dim3(640 / 128, 4096 / 32), 256, 0, stream>>>(w_kva, wkvaT, 4096, 576, 640, 1.0f);
    transpose_convert<<<dim3(6144 / 128, 1536 / 32), 256, 0, stream>>>(w_qb, wqbT, 1536, 6144, 6144, qscale);
    transpose_convert<<<dim3(8192 / 128, 512 / 32), 256, 0, stream>>>(w_kvb, wkvbT, 512, 8192, 8192, 1.0f);
    transpose_convert<<<dim3(4096 / 128, 4096 / 32), 256, 0, stream>>>(w_o, woT, 4096, 4096, 4096, 1.0f);

    // merged qa|kva GEMM: N = 1536 + 640 = 2176 = 17 x 128, split epilogue (1536 = 12*128)
    gemm_bt_128<2><<<dim3(17, 16), 256, 0, stream>>>(hid_b, wqaT, q_a, kv, 2048, 2176, 4096, 1536, 640);
    rmsnorm_kernel<<<2048, 256, 0, stream>>>(q_a, g_qa, q_c, 1536, 1536);
    rmsnorm_kernel<<<2048, 256, 0, stream>>>(kv, g_kva, k_c, 512, 640);
    rope_k_kernel<<<2048 * 32 / 256, 256, 0, stream>>>(kv, cos_t, sin_t, k_rope);
    gemm_bt_128<1><<<dim3(6144 / 128, 16), 256, 0, stream>>>(q_c, wqbT, q_buf, nullptr, 2048, 6144, 1536, 0, 0);
    rope_q_kernel<<<2048, 256, 0, stream>>>(q_buf, cos_t, sin_t);
    gemm_bt_128<1><<<dim3(8192 / 128, 16), 256, 0, stream>>>(k_c, wkvbT, kst, nullptr, 2048, 8192, 512, 0, 0);
    transpose_v_kernel<<<1024, 256, 0, stream>>>(kst, V_T);
    attn12_kernel<<<512, 512, 0, stream>>>(q_buf, kst, k_rope, V_T, attn_out);
    gemm_bt_128<0><<<dim3(4096 / 128, 16), 256, 0, stream>>>(attn_out, woT, out, nullptr, 2048, 4096, 4096, 0, 0);
}

// Round 13
// 456.201 us; speedup vs baseline: 1.0430x; 1.0430x over previous
//
#include <hip/hip_runtime.h>
#include <hip/hip_bf16.h>
#include <stdint.h>

typedef float f32x4_t __attribute__((ext_vector_type(4)));
typedef short s16x8_t __attribute__((ext_vector_type(8)));

#define LDS_AS __attribute__((address_space(3)))
#define GLB_AS __attribute__((address_space(1)))

__device__ __forceinline__ void gload16(void* lds, const void* g) {
    __builtin_amdgcn_global_load_lds((const GLB_AS uint32_t*)g,
                                     (LDS_AS uint32_t*)lds, 16, 0, 0);
}

__device__ __forceinline__ uint32_t pack_bf16(float lo, float hi) {
    union { __hip_bfloat16 h; uint16_t u; } a, b;
    a.h = __float2bfloat16(lo); b.h = __float2bfloat16(hi);
    return (uint32_t)a.u | ((uint32_t)b.u << 16);
}

// ---------------- RoPE table: cos/sin[s][j], j in [0,64), invf index j&31 ----------------
__global__ __launch_bounds__(256) void rope_table_kernel(float* __restrict__ cos_t,
                                                         float* __restrict__ sin_t) {
    int idx = blockIdx.x * 256 + threadIdx.x;       // 1024*64 exact
    int s = idx >> 6, j = idx & 63;
    float invf = powf(10000.0f, -((float)((j & 31) * 2)) / 64.0f);
    float a = (float)s * invf;
    cos_t[idx] = cosf(a);
    sin_t[idx] = sinf(a);
}

// ---------------- fp32 -> bf16 convert (x4 vectorized) ----------------
__global__ __launch_bounds__(256) void f32_to_bf16_kernel(const float* __restrict__ in,
                                                          __hip_bfloat16* __restrict__ out, int n4) {
    int i = blockIdx.x * 256 + threadIdx.x;
    if (i >= n4) return;
    float4 v = reinterpret_cast<const float4*>(in)[i];
    struct __align__(8) BF4 { __hip_bfloat16 a, b, c, d; } r;
    r.a = __float2bfloat16(v.x); r.b = __float2bfloat16(v.y);
    r.c = __float2bfloat16(v.z); r.d = __float2bfloat16(v.w);
    reinterpret_cast<BF4*>(out)[i] = r;
}

// ------- transpose + convert + scale (vectorized): W[K][N] f32 -> WT[Npad][K] bf16 -------
__global__ __launch_bounds__(256) void transpose_convert(const float* __restrict__ W,
                                                         __hip_bfloat16* __restrict__ WT,
                                                         int K, int N, int Npad, float scale) {
    __shared__ float tile[32][132];
    int k0 = blockIdx.y * 32, n0 = blockIdx.x * 128;
    int tx = threadIdx.x & 31, ty = threadIdx.x >> 5;   // tx: n-quad, ty: k-row
#pragma unroll
    for (int i = 0; i < 4; i++) {
        int ky = i * 8 + ty;
        int n = n0 + tx * 4;
        float4 v;
        if (n + 3 < N) {
            v = *(const float4*)&W[(size_t)(k0 + ky) * N + n];
        } else {
            float t0 = (n + 0 < N) ? W[(size_t)(k0 + ky) * N + n + 0] : 0.f;
            float t1 = (n + 1 < N) ? W[(size_t)(k0 + ky) * N + n + 1] : 0.f;
            float t2 = (n + 2 < N) ? W[(size_t)(k0 + ky) * N + n + 2] : 0.f;
            float t3 = (n + 3 < N) ? W[(size_t)(k0 + ky) * N + n + 3] : 0.f;
            v = make_float4(t0, t1, t2, t3);
        }
        *(float4*)&tile[ky][tx * 4] = v;
    }
    __syncthreads();
    int ny = threadIdx.x & 127, kh = threadIdx.x >> 7;   // ny 0..127, kh 0..1
#pragma unroll
    for (int oct = 0; oct < 2; oct++) {
        int kb = kh * 16 + oct * 8;
        union { short s[8]; s16x8_t v; } pk;
#pragma unroll
        for (int e = 0; e < 8; e++) {
            union { __hip_bfloat16 h; short s; } cv;
            cv.h = __float2bfloat16(tile[kb + e][ny] * scale);
            pk.s[e] = cv.s;
        }
        *(s16x8_t*)&WT[(size_t)(n0 + ny) * K + k0 + kb] = pk.v;
    }
}

// ------- rmsnorm over SUM of two f32 partials: (in0+in1) -> bf16 out ---------------------
__global__ __launch_bounds__(256) void rmsnorm2_kernel(const float* __restrict__ in0,
                                                       const float* __restrict__ in1,
                                                       const float* __restrict__ g,
                                                       __hip_bfloat16* __restrict__ out,
                                                       int cols, int in_stride) {
    int row = blockIdx.x;
    const float* x0 = in0 + (size_t)row * in_stride;
    const float* x1 = in1 + (size_t)row * in_stride;
    float ss = 0.f;
    for (int c = threadIdx.x; c < cols; c += 256) { float v = x0[c] + x1[c]; ss += v * v; }
#pragma unroll
    for (int off = 32; off > 0; off >>= 1) ss += __shfl_xor(ss, off);
    __shared__ float red[4];
    if ((threadIdx.x & 63) == 0) red[threadIdx.x >> 6] = ss;
    __syncthreads();
    float tot = red[0] + red[1] + red[2] + red[3];
    float rms = sqrtf(tot / (float)cols);
    float inv = 1.0f / (rms + 1e-6f);
    for (int c = threadIdx.x; c < cols; c += 256)
        out[(size_t)row * cols + c] = __float2bfloat16((x0[c] + x1[c]) * inv * g[c]);
}

// ------- k_rope from SUM of partials: (kv0+kv1)[tok][512..575] -> roped bf16 [tok][64] ----
__global__ __launch_bounds__(256) void rope_k2_kernel(const float* __restrict__ kv0,
                                                      const float* __restrict__ kv1,
                                                      const float* __restrict__ cos_t,
                                                      const float* __restrict__ sin_t,
                                                      __hip_bfloat16* __restrict__ k_rope) {
    int idx = blockIdx.x * 256 + threadIdx.x;       // 2048*32 exact
    int tok = idx >> 5, j = idx & 31;
    int s = tok & 1023;
    size_t base = (size_t)tok * 640 + 512;
    float x1 = kv0[base + j] + kv1[base + j];
    float x2 = kv0[base + j + 32] + kv1[base + j + 32];
    float co = cos_t[s * 64 + j], si = sin_t[s * 64 + j];
    __hip_bfloat16* o = k_rope + (size_t)tok * 64;
    o[j]      = __float2bfloat16(x1 * co - x2 * si);
    o[j + 32] = __float2bfloat16(x2 * co + x1 * si);
}

// ---------------- V transpose: kst[tok][h*256+128..255] -> V_T[bh][vd][1024] -------------
__global__ __launch_bounds__(256) void transpose_v_kernel(const __hip_bfloat16* __restrict__ kst,
                                                          __hip_bfloat16* __restrict__ V_T) {
    __shared__ __hip_bfloat16 t[64][136];
    int bid = blockIdx.x;                 // (b*32+h)*16 + st
    int st = bid & 15, bh = bid >> 4;
    int h = bh & 31, b = bh >> 5;
    int s0 = st * 64;
#pragma unroll
    for (int i = 0; i < 4; i++) {
        int c = i * 256 + threadIdx.x;    // 64 rows x 16 octs
        int r = c >> 4, oct = c & 15;
        *(s16x8_t*)&t[r][oct * 8] =
            *(const s16x8_t*)&kst[(size_t)(b * 1024 + s0 + r) * 8192 + h * 256 + 128 + oct * 8];
    }
    __syncthreads();
#pragma unroll
    for (int i = 0; i < 4; i++) {
        int c = i * 256 + threadIdx.x;    // 128 vd x 8 octs
        int vd = c >> 3, oct = c & 7;
        s16x8_t pk;
#pragma unroll
        for (int e = 0; e < 8; e++) pk[e] = *(const short*)&t[oct * 8 + e][vd];
        *(s16x8_t*)&V_T[((size_t)bh * 128 + vd) * 1024 + s0 + oct * 8] = pk;
    }
}

// ---------------- GEMM: A[M][Kstride] bf16 x BT[N][Kstride] bf16 -> C ---------------------
// MODE 0: f32 C[M][N]. MODE 1: bf16 C[M][N].
// MODE 2: K-split (gridDim.z parts; part z covers K cols [z*K, z*K+K)) + split f32 output
//   (col<N0 -> part? Cout2:Cout stride N0, else part? C12:C1 stride N1).
// MODE 3: bf16 C[M][N] + fused RoPE on blocks where (col/64)%3==2 (q layout NH x 192,
//   rope = cols 128..191 of each head; pairs are acc[m][n] / acc[m][n+-2], same thread).
template <int MODE>
__global__ __launch_bounds__(256, 3) void gemm_bt_128(const __hip_bfloat16* __restrict__ A,
                                                      const __hip_bfloat16* __restrict__ BT,
                                                      void* __restrict__ Cout, void* __restrict__ C1,
                                                      void* __restrict__ Cout2, void* __restrict__ C12,
                                                      int M, int N, int K, int Kstride, int N0, int N1,
                                                      const float* __restrict__ cos_t,
                                                      const float* __restrict__ sin_t) {
    __shared__ __hip_bfloat16 As[128 * 64];
    __shared__ __hip_bfloat16 Bs[128 * 64];
    const int tid = threadIdx.x;
    const int l = tid & 63, w = tid >> 6;
    const int wr = w >> 1, wc = w & 1;
    const int m0 = blockIdx.y * 128, n0 = blockIdx.x * 128;
    const int lrow = l & 15, lkg = l >> 4;
    const int part = (MODE == 2) ? blockIdx.z : 0;
    const int kbase = part * K;

    f32x4_t acc[4][4];
#pragma unroll
    for (int i = 0; i < 4; i++)
#pragma unroll
        for (int j = 0; j < 4; j++) acc[i][j] = (f32x4_t){0.f, 0.f, 0.f, 0.f};

    for (int k0 = 0; k0 < K; k0 += 64) {
        __syncthreads();
#pragma unroll
        for (int i = 0; i < 4; i++) {
            int s = i * 256 + tid;          // 1024 16B slots per tile
            int row = s >> 3, po = s & 7;
            int lo = po ^ (row & 7);        // logical k-octet for this physical slot
            gload16(&As[s * 8], &A[(size_t)(m0 + row) * Kstride + kbase + k0 + lo * 8]);
            gload16(&Bs[s * 8], &BT[(size_t)(n0 + row) * Kstride + kbase + k0 + lo * 8]);
        }
        __syncthreads();
#pragma unroll
        for (int ks = 0; ks < 2; ks++) {
            s16x8_t a[4], b[4];
#pragma unroll
            for (int m = 0; m < 4; m++) {
                int row = wr * 64 + m * 16 + lrow;
                int oct = (ks * 4 + lkg) ^ (row & 7);
                a[m] = *(const s16x8_t*)&As[row * 64 + oct * 8];
            }
#pragma unroll
            for (int n = 0; n < 4; n++) {
                int row = wc * 64 + n * 16 + lrow;
                int oct = (ks * 4 + lkg) ^ (row & 7);
                b[n] = *(const s16x8_t*)&Bs[row * 64 + oct * 8];
            }
#pragma unroll
            for (int m = 0; m < 4; m++)
#pragma unroll
                for (int n = 0; n < 4; n++)
                    acc[m][n] = __builtin_amdgcn_mfma_f32_16x16x32_bf16(a[m], b[n], acc[m][n], 0, 0, 0);
        }
    }
    const bool ropeblk = (MODE == 3) && ((((n0 + wc * 64) >> 6) % 3) == 2);
#pragma unroll
    for (int m = 0; m < 4; m++) {
        int row = m0 + wr * 64 + m * 16 + lkg * 4;
#pragma unroll
        for (int n = 0; n < 4; n++) {
            int col = n0 + wc * 64 + n * 16 + lrow;
#pragma unroll
            for (int r = 0; r < 4; r++) {
                float v = acc[m][n][r];
                if (MODE == 3 && ropeblk) {
                    int s = (row + r) & 1023;
                    int j = ((n & 1) << 4) + lrow;
                    float co = cos_t[s * 64 + j], si = sin_t[s * 64 + j];
                    v = (n < 2) ? acc[m][n][r] * co - acc[m][n + 2][r] * si
                                : acc[m][n][r] * co + acc[m][n - 2][r] * si;
                }
                if (MODE == 1 || MODE == 3) {
                    ((__hip_bfloat16*)Cout)[(size_t)(row + r) * N + col] = __float2bfloat16(v);
                } else if (MODE == 0) {
                    ((float*)Cout)[(size_t)(row + r) * N + col] = v;
                } else {
                    float* c0 = (float*)(part ? Cout2 : Cout);
                    float* c1 = (float*)(part ? C12 : C1);
                    if (col < N0) c0[(size_t)(row + r) * N0 + col] = v;
                    else          c1[(size_t)(row + r) * N1 + (col - N0)] = v;
                }
            }
        }
    }
}

// ---------------- attention v8 (validated 149.6us): swapped QK^T, no P-LDS ---------------
__global__ __launch_bounds__(256, 3) void attn8_kernel(const __hip_bfloat16* __restrict__ q,
                                                       const __hip_bfloat16* __restrict__ kst,
                                                       const __hip_bfloat16* __restrict__ k_rope,
                                                       const __hip_bfloat16* __restrict__ V_T,
                                                       __hip_bfloat16* __restrict__ attn_out) {
    __shared__ __align__(16) __hip_bfloat16 Ks[2][64 * 192];  // 48 KB total

    int i = blockIdx.x;                       // grid 1024
    int bh = (i & 7) * 8 + ((i >> 3) & 7);
    int qt = i >> 6;                          // [0,16)
    int h = bh & 31, b = bh >> 5;
    int q0 = qt * 64;
    int tid = threadIdx.x, l = tid & 63, w = tid >> 6;
    int lrow = l & 15, lkg = l >> 4;

    s16x8_t qa[6];
    {
        size_t qbase = (size_t)(b * 1024 + q0 + w * 16 + lrow) * 6144 + h * 192;
#pragma unroll
        for (int f = 0; f < 6; f++)
            qa[f] = *(const s16x8_t*)&q[qbase + f * 32 + lkg * 8];
    }
    f32x4_t acc_o[8];
#pragma unroll
    for (int n = 0; n < 8; n++) acc_o[n] = (f32x4_t){0.f, 0.f, 0.f, 0.f};
    float m_run = -1e30f, l_run = 0.f;

    size_t krow_base = (size_t)(b * 1024) * 8192 + h * 256;
    size_t rrow_base = (size_t)(b * 1024) * 64;
    const __hip_bfloat16* vbase = V_T + (size_t)bh * 128 * 1024 + (size_t)lrow * 1024 + lkg * 8;

    auto stage_k = [&](int kv0, int buf) {
#pragma unroll
        for (int it = 0; it < 6; it++) {
            int s = it * 256 + tid;               // 0..1535
            int row = s / 24, po = s - row * 24;
            int lo = po ^ (row & 7);
            const __hip_bfloat16* src = (lo < 16)
                ? &kst[krow_base + (size_t)(kv0 + row) * 8192 + lo * 8]
                : &k_rope[rrow_base + (size_t)(kv0 + row) * 64 + (lo - 16) * 8];
            gload16(&Ks[buf][s * 8], src);
        }
    };

    stage_k(0, 0);
    asm volatile("s_waitcnt vmcnt(0)" ::: "memory");
    __syncthreads();

    const int src0 = lrow + ((lkg & 1) << 5);
    const int src1 = src0 + 16;
    const bool hiC = (lkg >> 1) != 0;

    int cur = 0;
    for (int kt = 0; kt < 16; kt++) {
        int kv0 = kt * 64;

        if (kt < 15) stage_k(kv0 + 64, cur ^ 1);

        f32x4_t sc[4];
#pragma unroll
        for (int c = 0; c < 4; c++) sc[c] = (f32x4_t){0.f, 0.f, 0.f, 0.f};
        __builtin_amdgcn_s_setprio(1);
#pragma unroll
        for (int c = 0; c < 4; c++) {
            int row = c * 16 + lrow;
#pragma unroll
            for (int f = 0; f < 6; f++) {
                int po = ((f * 4 + lkg) ^ (lrow & 7)) * 8;
                s16x8_t kb = *(const s16x8_t*)&Ks[cur][row * 192 + po];
                sc[c] = __builtin_amdgcn_mfma_f32_16x16x32_bf16(kb, qa[f], sc[c], 0, 0, 0);
            }
        }
        __builtin_amdgcn_s_setprio(0);

        s16x8_t vb0[8];
#pragma unroll
        for (int n = 0; n < 8; n++)
            vb0[n] = *(const s16x8_t*)&vbase[(size_t)(n * 16) * 1024 + kv0];
        __builtin_amdgcn_sched_barrier(0);

        float mx = sc[0][0];
#pragma unroll
        for (int c = 0; c < 4; c++)
#pragma unroll
            for (int r = 0; r < 4; r++) mx = fmaxf(mx, sc[c][r]);
        mx = fmaxf(mx, __shfl_xor(mx, 16));
        mx = fmaxf(mx, __shfl_xor(mx, 32));
        if (!__all(mx - m_run <= 8.0f)) {
            float mn = fmaxf(m_run, mx);
            float al = __expf(m_run - mn);
            m_run = mn;
            l_run *= al;
#pragma unroll
            for (int n = 0; n < 8; n++) acc_o[n] *= al;
        }
        uint32_t u[4][2];
        float sum = 0.f;
#pragma unroll
        for (int c = 0; c < 4; c++) {
            float p0 = __expf(sc[c][0] - m_run), p1 = __expf(sc[c][1] - m_run);
            float p2 = __expf(sc[c][2] - m_run), p3 = __expf(sc[c][3] - m_run);
            sum += (p0 + p1) + (p2 + p3);
            u[c][0] = pack_bf16(p0, p1);
            u[c][1] = pack_bf16(p2, p3);
        }
        sum += __shfl_xor(sum, 16);
        sum += __shfl_xor(sum, 32);
        l_run += sum;

        {
            uint32_t a0 = __shfl((int)u[0][0], src0), b0 = __shfl((int)u[1][0], src0);
            uint32_t a1 = __shfl((int)u[0][1], src0), b1 = __shfl((int)u[1][1], src0);
            uint32_t a2 = __shfl((int)u[0][0], src1), b2 = __shfl((int)u[1][0], src1);
            uint32_t a3 = __shfl((int)u[0][1], src1), b3 = __shfl((int)u[1][1], src1);
            union { uint32_t wd[4]; s16x8_t v; } pb;
            pb.wd[0] = hiC ? b0 : a0;
            pb.wd[1] = hiC ? b1 : a1;
            pb.wd[2] = hiC ? b2 : a2;
            pb.wd[3] = hiC ? b3 : a3;
            __builtin_amdgcn_s_setprio(1);
#pragma unroll
            for (int n = 0; n < 8; n++)
                acc_o[n] = __builtin_amdgcn_mfma_f32_16x16x32_bf16(vb0[n], pb.v, acc_o[n], 0, 0, 0);
            __builtin_amdgcn_s_setprio(0);
        }
        s16x8_t vb1[8];
#pragma unroll
        for (int n = 0; n < 8; n++)
            vb1[n] = *(const s16x8_t*)&vbase[(size_t)(n * 16) * 1024 + kv0 + 32];
        {
            uint32_t a0 = __shfl((int)u[2][0], src0), b0 = __shfl((int)u[3][0], src0);
            uint32_t a1 = __shfl((int)u[2][1], src0), b1 = __shfl((int)u[3][1], src0);
            uint32_t a2 = __shfl((int)u[2][0], src1), b2 = __shfl((int)u[3][0], src1);
            uint32_t a3 = __shfl((int)u[2][1], src1), b3 = __shfl((int)u[3][1], src1);
            union { uint32_t wd[4]; s16x8_t v; } pb;
            pb.wd[0] = hiC ? b0 : a0;
            pb.wd[1] = hiC ? b1 : a1;
            pb.wd[2] = hiC ? b2 : a2;
            pb.wd[3] = hiC ? b3 : a3;
            __builtin_amdgcn_s_setprio(1);
#pragma unroll
            for (int n = 0; n < 8; n++)
                acc_o[n] = __builtin_amdgcn_mfma_f32_16x16x32_bf16(vb1[n], pb.v, acc_o[n], 0, 0, 0);
            __builtin_amdgcn_s_setprio(0);
        }

        asm volatile("s_waitcnt vmcnt(0)" ::: "memory");
        __syncthreads();
        cur ^= 1;
    }

    float inv = 1.0f / l_run;
    __hip_bfloat16* Ob = &Ks[0][0] + (size_t)w * (16 * 136);   // 16 rows x 136 (pad)
#pragma unroll
    for (int n = 0; n < 8; n++) {
        uint32_t lo = pack_bf16(acc_o[n][0] * inv, acc_o[n][1] * inv);
        uint32_t hi = pack_bf16(acc_o[n][2] * inv, acc_o[n][3] * inv);
        uint32_t* dst = (uint32_t*)&Ob[lrow * 136 + n * 16 + lkg * 4];
        dst[0] = lo;
        dst[1] = hi;
    }
    asm volatile("s_waitcnt lgkmcnt(0)" ::: "memory");
    __builtin_amdgcn_sched_barrier(0);
#pragma unroll
    for (int it = 0; it < 4; it++) {
        int tr = it * 4 + lkg;
        s16x8_t ov = *(const s16x8_t*)&Ob[tr * 136 + lrow * 8];
        *(s16x8_t*)&attn_out[(size_t)(b * 1024 + q0 + w * 16 + tr) * 4096 + h * 128 + lrow * 8] = ov;
    }
}

extern "C" void kernel_launch(void* const* d_in, const int* in_sizes, int n_in,
                              void* d_out, int out_size, void* d_ws, size_t ws_size,
                              hipStream_t stream) {
    const float* hidden = (const float*)d_in[0];
    const float* w_qa   = (const float*)d_in[1];
    const float* g_qa   = (const float*)d_in[2];
    const float* w_qb   = (const float*)d_in[3];
    const float* w_kva  = (const float*)d_in[4];
    const float* g_kva  = (const float*)d_in[5];
    const float* w_kvb  = (const float*)d_in[6];
    const float* w_o    = (const float*)d_in[7];
    float* out = (float*)d_out;

    char* base = (char*)d_ws;
    size_t off = 0;
    auto alloc = [&](size_t bytes) -> void* {
        off = (off + 255) & ~(size_t)255;
        void* p = base + off;
        off += bytes;
        return p;
    };
    float* cos_t = (float*)alloc(1024 * 64 * 4);
    float* sin_t = (float*)alloc(1024 * 64 * 4);
    __hip_bfloat16* hid_b  = (__hip_bfloat16*)alloc(2048ull * 4096 * 2);  // later reused as V_T
    // wqaT and wkvaT MUST be adjacent+contiguous: combined BT [2176][4096] for merged GEMM.
    __hip_bfloat16* wqaT   = (__hip_bfloat16*)alloc(1536ull * 4096 * 2);  // 12582912 B, 256-aligned
    __hip_bfloat16* wkvaT  = (__hip_bfloat16*)alloc(640ull * 4096 * 2);   // = wqaT + 1536*4096
    __hip_bfloat16* wqbT   = (__hip_bfloat16*)alloc(6144ull * 1536 * 2);  // later reused as attn_out
    __hip_bfloat16* wkvbT  = (__hip_bfloat16*)alloc(8192ull * 512 * 2);
    __hip_bfloat16* woT    = (__hip_bfloat16*)alloc(4096ull * 4096 * 2);
    float* q_a             = (float*)alloc(2048ull * 1536 * 4);           // K-split part 0
    __hip_bfloat16* q_c    = (__hip_bfloat16*)alloc(2048ull * 1536 * 2);
    __hip_bfloat16* q_buf  = (__hip_bfloat16*)alloc(2048ull * 6144 * 2);  // part-1 overlay until qb GEMM
    float* kv              = (float*)alloc(2048ull * 640 * 4);            // K-split part 0
    __hip_bfloat16* k_c    = (__hip_bfloat16*)alloc(2048ull * 512 * 2);
    __hip_bfloat16* k_rope = (__hip_bfloat16*)alloc(2048ull * 64 * 2);
    __hip_bfloat16* kst    = (__hip_bfloat16*)alloc(2048ull * 8192 * 2);
    __hip_bfloat16* V_T      = hid_b;   // hid_b dead after the merged first GEMM
    __hip_bfloat16* attn_out = wqbT;    // wqbT dead after q GEMM
    // K-split part-1 outputs overlaid on q_buf (q_buf not written until qb GEMM,
    // which runs after rmsnorm2/rope_k2 consume the parts): 12.6MB + 5.2MB <= 25.2MB.
    float* q_a1 = (float*)q_buf;
    float* kv1  = (float*)((char*)q_buf + 2048ull * 1536 * 4);

    const float qscale = 0.07216878364870323f;   // 192^-0.5, folded into w_qb

    rope_table_kernel<<<256, 256, 0, stream>>>(cos_t, sin_t);
    f32_to_bf16_kernel<<<8192, 256, 0, stream>>>(hidden, hid_b, 2048 * 4096 / 4);
    transpose_convert<<<dim3(1536 / 128, 4096 / 32), 256, 0, stream>>>(w_qa, wqaT, 4096, 1536, 1536, 1.0f);
    transpose_convert<<<dim3(640 / 128, 4096 / 32), 256, 0, stream>>>(w_kva, wkvaT, 4096, 576, 640, 1.0f);
    transpose_convert<<<dim3(6144 / 128, 1536 / 32), 256, 0, stream>>>(w_qb, wqbT, 1536, 6144, 6144, qscale);
    transpose_convert<<<dim3(8192 / 128, 512 / 32), 256, 0, stream>>>(w_kvb, wkvbT, 512, 8192, 8192, 1.0f);
    transpose_convert<<<dim3(4096 / 128, 4096 / 32), 256, 0, stream>>>(w_o, woT, 4096, 4096, 4096, 1.0f);

    // merged qa|kva GEMM, K-split x2: grid (17,16,2); part z covers K in [z*2048,(z+1)*2048)
    gemm_bt_128<2><<<dim3(17, 16, 2), 256, 0, stream>>>(hid_b, wqaT, q_a, kv, q_a1, kv1,
                                                        2048, 2176, 2048, 4096, 1536, 640,
                                                        nullptr, nullptr);
    rmsnorm2_kernel<<<2048, 256, 0, stream>>>(q_a, q_a1, g_qa, q_c, 1536, 1536);
    rmsnorm2_kernel<<<2048, 256, 0, stream>>>(kv, kv1, g_kva, k_c, 512, 640);
    rope_k2_kernel<<<2048 * 32 / 256, 256, 0, stream>>>(kv, kv1, cos_t, sin_t, k_rope);
    // qb GEMM with fused rope (MODE 3) -> q_buf (overwrites the part-1 overlay, now dead)
    gemm_bt_128<3><<<dim3(6144 / 128, 16), 256, 0, stream>>>(q_c, wqbT, q_buf, nullptr, nullptr, nullptr,
                                                             2048, 6144, 1536, 1536, 0, 0, cos_t, sin_t);
    gemm_bt_128<1><<<dim3(8192 / 128, 16), 256, 0, stream>>>(k_c, wkvbT, kst, nullptr, nullptr, nullptr,
                                                             2048, 8192, 512, 512, 0, 0, nullptr, nullptr);
    transpose_v_kernel<<<1024, 256, 0, stream>>>(kst, V_T);
    attn8_kernel<<<1024, 256, 0, stream>>>(q_buf, kst, k_rope, V_T, attn_out);
    gemm_bt_128<0><<<dim3(4096 / 128, 16), 256, 0, stream>>>(attn_out, woT, out, nullptr, nullptr, nullptr,
                                                             2048, 4096, 4096, 4096, 0, 0, nullptr, nullptr);
}

// Round 15
// 442.541 us; speedup vs baseline: 1.0752x; 1.0309x over previous
//
#include <hip/hip_runtime.h>
#include <hip/hip_bf16.h>
#include <stdint.h>

typedef float f32x4_t __attribute__((ext_vector_type(4)));
typedef short s16x8_t __attribute__((ext_vector_type(8)));

#define LDS_AS __attribute__((address_space(3)))
#define GLB_AS __attribute__((address_space(1)))

__device__ __forceinline__ void gload16(void* lds, const void* g) {
    __builtin_amdgcn_global_load_lds((const GLB_AS uint32_t*)g,
                                     (LDS_AS uint32_t*)lds, 16, 0, 0);
}

__device__ __forceinline__ uint32_t pack_bf16(float lo, float hi) {
    union { __hip_bfloat16 h; uint16_t u; } a, b;
    a.h = __float2bfloat16(lo); b.h = __float2bfloat16(hi);
    return (uint32_t)a.u | ((uint32_t)b.u << 16);
}

// ---------------- RoPE table: cos/sin[s][j], j in [0,64), invf index j&31 ----------------
__global__ __launch_bounds__(256) void rope_table_kernel(float* __restrict__ cos_t,
                                                         float* __restrict__ sin_t) {
    int idx = blockIdx.x * 256 + threadIdx.x;       // 1024*64 exact
    int s = idx >> 6, j = idx & 63;
    float invf = powf(10000.0f, -((float)((j & 31) * 2)) / 64.0f);
    float a = (float)s * invf;
    cos_t[idx] = cosf(a);
    sin_t[idx] = sinf(a);
}

// ---------------- fp32 -> bf16 convert (x4 vectorized) ----------------
__global__ __launch_bounds__(256) void f32_to_bf16_kernel(const float* __restrict__ in,
                                                          __hip_bfloat16* __restrict__ out, int n4) {
    int i = blockIdx.x * 256 + threadIdx.x;
    if (i >= n4) return;
    float4 v = reinterpret_cast<const float4*>(in)[i];
    struct __align__(8) BF4 { __hip_bfloat16 a, b, c, d; } r;
    r.a = __float2bfloat16(v.x); r.b = __float2bfloat16(v.y);
    r.c = __float2bfloat16(v.z); r.d = __float2bfloat16(v.w);
    reinterpret_cast<BF4*>(out)[i] = r;
}

// ------- transpose + convert + scale (vectorized): W[K][N] f32 -> WT[Npad][K] bf16 -------
__global__ __launch_bounds__(256) void transpose_convert(const float* __restrict__ W,
                                                         __hip_bfloat16* __restrict__ WT,
                                                         int K, int N, int Npad, float scale) {
    __shared__ float tile[32][132];
    int k0 = blockIdx.y * 32, n0 = blockIdx.x * 128;
    int tx = threadIdx.x & 31, ty = threadIdx.x >> 5;   // tx: n-quad, ty: k-row
#pragma unroll
    for (int i = 0; i < 4; i++) {
        int ky = i * 8 + ty;
        int n = n0 + tx * 4;
        float4 v;
        if (n + 3 < N) {
            v = *(const float4*)&W[(size_t)(k0 + ky) * N + n];
        } else {
            float t0 = (n + 0 < N) ? W[(size_t)(k0 + ky) * N + n + 0] : 0.f;
            float t1 = (n + 1 < N) ? W[(size_t)(k0 + ky) * N + n + 1] : 0.f;
            float t2 = (n + 2 < N) ? W[(size_t)(k0 + ky) * N + n + 2] : 0.f;
            float t3 = (n + 3 < N) ? W[(size_t)(k0 + ky) * N + n + 3] : 0.f;
            v = make_float4(t0, t1, t2, t3);
        }
        *(float4*)&tile[ky][tx * 4] = v;
    }
    __syncthreads();
    int ny = threadIdx.x & 127, kh = threadIdx.x >> 7;   // ny 0..127, kh 0..1
#pragma unroll
    for (int oct = 0; oct < 2; oct++) {
        int kb = kh * 16 + oct * 8;
        union { short s[8]; s16x8_t v; } pk;
#pragma unroll
        for (int e = 0; e < 8; e++) {
            union { __hip_bfloat16 h; short s; } cv;
            cv.h = __float2bfloat16(tile[kb + e][ny] * scale);
            pk.s[e] = cv.s;
        }
        *(s16x8_t*)&WT[(size_t)(n0 + ny) * K + k0 + kb] = pk.v;
    }
}

// ------- rmsnorm over SUM of two f32 partials: (in0+in1) -> bf16 out ---------------------
__global__ __launch_bounds__(256) void rmsnorm2_kernel(const float* __restrict__ in0,
                                                       const float* __restrict__ in1,
                                                       const float* __restrict__ g,
                                                       __hip_bfloat16* __restrict__ out,
                                                       int cols, int in_stride) {
    int row = blockIdx.x;
    const float* x0 = in0 + (size_t)row * in_stride;
    const float* x1 = in1 + (size_t)row * in_stride;
    float ss = 0.f;
    for (int c = threadIdx.x; c < cols; c += 256) { float v = x0[c] + x1[c]; ss += v * v; }
#pragma unroll
    for (int off = 32; off > 0; off >>= 1) ss += __shfl_xor(ss, off);
    __shared__ float red[4];
    if ((threadIdx.x & 63) == 0) red[threadIdx.x >> 6] = ss;
    __syncthreads();
    float tot = red[0] + red[1] + red[2] + red[3];
    float rms = sqrtf(tot / (float)cols);
    float inv = 1.0f / (rms + 1e-6f);
    for (int c = threadIdx.x; c < cols; c += 256)
        out[(size_t)row * cols + c] = __float2bfloat16((x0[c] + x1[c]) * inv * g[c]);
}

// ------- kv rmsnorm (cols 0..511) + fused k_rope (cols 512..575), both from partials -----
__global__ __launch_bounds__(256) void rmsnorm2_rope_kernel(const float* __restrict__ in0,
                                                            const float* __restrict__ in1,
                                                            const float* __restrict__ g,
                                                            __hip_bfloat16* __restrict__ out,
                                                            const float* __restrict__ cos_t,
                                                            const float* __restrict__ sin_t,
                                                            __hip_bfloat16* __restrict__ k_rope) {
    int row = blockIdx.x;                                  // token 0..2047
    const float* x0 = in0 + (size_t)row * 640;
    const float* x1 = in1 + (size_t)row * 640;
    float ss = 0.f;
#pragma unroll
    for (int it = 0; it < 2; it++) {
        int c = it * 256 + threadIdx.x;
        float v = x0[c] + x1[c];
        ss += v * v;
    }
#pragma unroll
    for (int off = 32; off > 0; off >>= 1) ss += __shfl_xor(ss, off);
    __shared__ float red[4];
    if ((threadIdx.x & 63) == 0) red[threadIdx.x >> 6] = ss;
    __syncthreads();
    float tot = red[0] + red[1] + red[2] + red[3];
    float rms = sqrtf(tot / 512.0f);
    float inv = 1.0f / (rms + 1e-6f);
#pragma unroll
    for (int it = 0; it < 2; it++) {
        int c = it * 256 + threadIdx.x;
        out[(size_t)row * 512 + c] = __float2bfloat16((x0[c] + x1[c]) * inv * g[c]);
    }
    // fused rope on cols 512..575 (independent of rms)
    if (threadIdx.x < 32) {
        int j = threadIdx.x, s = row & 1023;
        float a1 = x0[512 + j] + x1[512 + j];
        float a2 = x0[544 + j] + x1[544 + j];
        float co = cos_t[s * 64 + j], si = sin_t[s * 64 + j];
        __hip_bfloat16* o = k_rope + (size_t)row * 64;
        o[j]      = __float2bfloat16(a1 * co - a2 * si);
        o[j + 32] = __float2bfloat16(a2 * co + a1 * si);
    }
}

// ---------------- GEMM: A[M][Kstride] bf16 x BT[N][Kstride] bf16 -> C ---------------------
// MODE 0: f32 C[M][N]. MODE 1: bf16 C[M][N].
// MODE 2: K-split (gridDim.z parts) + split f32 output.
// MODE 3: bf16 C[M][N] + fused RoPE on blocks where (col/64)%3==2.
// MODE 4: kvb: nope cols -> kst bf16 (stride N); V cols ((col&255)>=128, wave-uniform
//   via ((n0+wc*64)>>7)&1) -> V_T[(b*32+h)*128+vd][s] transposed, 4 tokens packed per 8B.
template <int MODE>
__global__ __launch_bounds__(256, 3) void gemm_bt_128(const __hip_bfloat16* __restrict__ A,
                                                      const __hip_bfloat16* __restrict__ BT,
                                                      void* __restrict__ Cout, void* __restrict__ C1,
                                                      void* __restrict__ Cout2, void* __restrict__ C12,
                                                      int M, int N, int K, int Kstride, int N0, int N1,
                                                      const float* __restrict__ cos_t,
                                                      const float* __restrict__ sin_t) {
    __shared__ __hip_bfloat16 As[128 * 64];
    __shared__ __hip_bfloat16 Bs[128 * 64];
    const int tid = threadIdx.x;
    const int l = tid & 63, w = tid >> 6;
    const int wr = w >> 1, wc = w & 1;
    const int m0 = blockIdx.y * 128, n0 = blockIdx.x * 128;
    const int lrow = l & 15, lkg = l >> 4;
    const int part = (MODE == 2) ? blockIdx.z : 0;
    const int kbase = part * K;

    f32x4_t acc[4][4];
#pragma unroll
    for (int i = 0; i < 4; i++)
#pragma unroll
        for (int j = 0; j < 4; j++) acc[i][j] = (f32x4_t){0.f, 0.f, 0.f, 0.f};

    for (int k0 = 0; k0 < K; k0 += 64) {
        __syncthreads();
#pragma unroll
        for (int i = 0; i < 4; i++) {
            int s = i * 256 + tid;          // 1024 16B slots per tile
            int row = s >> 3, po = s & 7;
            int lo = po ^ (row & 7);        // logical k-octet for this physical slot
            gload16(&As[s * 8], &A[(size_t)(m0 + row) * Kstride + kbase + k0 + lo * 8]);
            gload16(&Bs[s * 8], &BT[(size_t)(n0 + row) * Kstride + kbase + k0 + lo * 8]);
        }
        __syncthreads();
#pragma unroll
        for (int ks = 0; ks < 2; ks++) {
            s16x8_t a[4], b[4];
#pragma unroll
            for (int m = 0; m < 4; m++) {
                int row = wr * 64 + m * 16 + lrow;
                int oct = (ks * 4 + lkg) ^ (row & 7);
                a[m] = *(const s16x8_t*)&As[row * 64 + oct * 8];
            }
#pragma unroll
            for (int n = 0; n < 4; n++) {
                int row = wc * 64 + n * 16 + lrow;
                int oct = (ks * 4 + lkg) ^ (row & 7);
                b[n] = *(const s16x8_t*)&Bs[row * 64 + oct * 8];
            }
#pragma unroll
            for (int m = 0; m < 4; m++)
#pragma unroll
                for (int n = 0; n < 4; n++)
                    acc[m][n] = __builtin_amdgcn_mfma_f32_16x16x32_bf16(a[m], b[n], acc[m][n], 0, 0, 0);
        }
    }
    const bool ropeblk = (MODE == 3) && ((((n0 + wc * 64) >> 6) % 3) == 2);
    const bool vpart   = (MODE == 4) && ((((n0 + wc * 64) >> 7) & 1) != 0);
#pragma unroll
    for (int m = 0; m < 4; m++) {
        int row = m0 + wr * 64 + m * 16 + lkg * 4;
#pragma unroll
        for (int n = 0; n < 4; n++) {
            int col = n0 + wc * 64 + n * 16 + lrow;
            if (MODE == 4 && vpart) {
                // transposed V_T write: 4 consecutive tokens (r=0..3) packed into 8B
                int h = col >> 8, vd = (col & 255) - 128;
                int bb = row >> 10, s = row & 1023;
                uint32_t lo = pack_bf16(acc[m][n][0], acc[m][n][1]);
                uint32_t hi = pack_bf16(acc[m][n][2], acc[m][n][3]);
                uint32_t* dst = (uint32_t*)((__hip_bfloat16*)Cout2 +
                                            ((size_t)((bb * 32 + h) * 128 + vd)) * 1024 + s);
                dst[0] = lo;
                dst[1] = hi;
                continue;
            }
#pragma unroll
            for (int r = 0; r < 4; r++) {
                float v = acc[m][n][r];
                if (MODE == 3 && ropeblk) {
                    int s = (row + r) & 1023;
                    int j = ((n & 1) << 4) + lrow;
                    float co = cos_t[s * 64 + j], si = sin_t[s * 64 + j];
                    v = (n < 2) ? acc[m][n][r] * co - acc[m][n + 2][r] * si
                                : acc[m][n][r] * co + acc[m][n - 2][r] * si;
                }
                if (MODE == 1 || MODE == 3 || MODE == 4) {
                    ((__hip_bfloat16*)Cout)[(size_t)(row + r) * N + col] = __float2bfloat16(v);
                } else if (MODE == 0) {
                    ((float*)Cout)[(size_t)(row + r) * N + col] = v;
                } else {
                    float* c0 = (float*)(part ? Cout2 : Cout);
                    float* c1 = (float*)(part ? C12 : C1);
                    if (col < N0) c0[(size_t)(row + r) * N0 + col] = v;
                    else          c1[(size_t)(row + r) * N1 + (col - N0)] = v;
                }
            }
        }
    }
}

// ---------------- attention v8 (validated 149.6us): swapped QK^T, no P-LDS ---------------
__global__ __launch_bounds__(256, 3) void attn8_kernel(const __hip_bfloat16* __restrict__ q,
                                                       const __hip_bfloat16* __restrict__ kst,
                                                       const __hip_bfloat16* __restrict__ k_rope,
                                                       const __hip_bfloat16* __restrict__ V_T,
                                                       __hip_bfloat16* __restrict__ attn_out) {
    __shared__ __align__(16) __hip_bfloat16 Ks[2][64 * 192];  // 48 KB total

    int i = blockIdx.x;                       // grid 1024
    int bh = (i & 7) * 8 + ((i >> 3) & 7);
    int qt = i >> 6;                          // [0,16)
    int h = bh & 31, b = bh >> 5;
    int q0 = qt * 64;
    int tid = threadIdx.x, l = tid & 63, w = tid >> 6;
    int lrow = l & 15, lkg = l >> 4;

    s16x8_t qa[6];
    {
        size_t qbase = (size_t)(b * 1024 + q0 + w * 16 + lrow) * 6144 + h * 192;
#pragma unroll
        for (int f = 0; f < 6; f++)
            qa[f] = *(const s16x8_t*)&q[qbase + f * 32 + lkg * 8];
    }
    f32x4_t acc_o[8];
#pragma unroll
    for (int n = 0; n < 8; n++) acc_o[n] = (f32x4_t){0.f, 0.f, 0.f, 0.f};
    float m_run = -1e30f, l_run = 0.f;

    size_t krow_base = (size_t)(b * 1024) * 8192 + h * 256;
    size_t rrow_base = (size_t)(b * 1024) * 64;
    const __hip_bfloat16* vbase = V_T + (size_t)bh * 128 * 1024 + (size_t)lrow * 1024 + lkg * 8;

    auto stage_k = [&](int kv0, int buf) {
#pragma unroll
        for (int it = 0; it < 6; it++) {
            int s = it * 256 + tid;               // 0..1535
            int row = s / 24, po = s - row * 24;
            int lo = po ^ (row & 7);
            const __hip_bfloat16* src = (lo < 16)
                ? &kst[krow_base + (size_t)(kv0 + row) * 8192 + lo * 8]
                : &k_rope[rrow_base + (size_t)(kv0 + row) * 64 + (lo - 16) * 8];
            gload16(&Ks[buf][s * 8], src);
        }
    };

    stage_k(0, 0);
    asm volatile("s_waitcnt vmcnt(0)" ::: "memory");
    __syncthreads();

    const int src0 = lrow + ((lkg & 1) << 5);
    const int src1 = src0 + 16;
    const bool hiC = (lkg >> 1) != 0;

    int cur = 0;
    for (int kt = 0; kt < 16; kt++) {
        int kv0 = kt * 64;

        if (kt < 15) stage_k(kv0 + 64, cur ^ 1);

        f32x4_t sc[4];
#pragma unroll
        for (int c = 0; c < 4; c++) sc[c] = (f32x4_t){0.f, 0.f, 0.f, 0.f};
        __builtin_amdgcn_s_setprio(1);
#pragma unroll
        for (int c = 0; c < 4; c++) {
            int row = c * 16 + lrow;
#pragma unroll
            for (int f = 0; f < 6; f++) {
                int po = ((f * 4 + lkg) ^ (lrow & 7)) * 8;
                s16x8_t kb = *(const s16x8_t*)&Ks[cur][row * 192 + po];
                sc[c] = __builtin_amdgcn_mfma_f32_16x16x32_bf16(kb, qa[f], sc[c], 0, 0, 0);
            }
        }
        __builtin_amdgcn_s_setprio(0);

        s16x8_t vb0[8];
#pragma unroll
        for (int n = 0; n < 8; n++)
            vb0[n] = *(const s16x8_t*)&vbase[(size_t)(n * 16) * 1024 + kv0];
        __builtin_amdgcn_sched_barrier(0);

        float mx = sc[0][0];
#pragma unroll
        for (int c = 0; c < 4; c++)
#pragma unroll
            for (int r = 0; r < 4; r++) mx = fmaxf(mx, sc[c][r]);
        mx = fmaxf(mx, __shfl_xor(mx, 16));
        mx = fmaxf(mx, __shfl_xor(mx, 32));
        if (!__all(mx - m_run <= 8.0f)) {
            float mn = fmaxf(m_run, mx);
            float al = __expf(m_run - mn);
            m_run = mn;
            l_run *= al;
#pragma unroll
            for (int n = 0; n < 8; n++) acc_o[n] *= al;
        }
        uint32_t u[4][2];
        float sum = 0.f;
#pragma unroll
        for (int c = 0; c < 4; c++) {
            float p0 = __expf(sc[c][0] - m_run), p1 = __expf(sc[c][1] - m_run);
            float p2 = __expf(sc[c][2] - m_run), p3 = __expf(sc[c][3] - m_run);
            sum += (p0 + p1) + (p2 + p3);
            u[c][0] = pack_bf16(p0, p1);
            u[c][1] = pack_bf16(p2, p3);
        }
        sum += __shfl_xor(sum, 16);
        sum += __shfl_xor(sum, 32);
        l_run += sum;

        {
            uint32_t a0 = __shfl((int)u[0][0], src0), b0 = __shfl((int)u[1][0], src0);
            uint32_t a1 = __shfl((int)u[0][1], src0), b1 = __shfl((int)u[1][1], src0);
            uint32_t a2 = __shfl((int)u[0][0], src1), b2 = __shfl((int)u[1][0], src1);
            uint32_t a3 = __shfl((int)u[0][1], src1), b3 = __shfl((int)u[1][1], src1);
            union { uint32_t wd[4]; s16x8_t v; } pb;
            pb.wd[0] = hiC ? b0 : a0;
            pb.wd[1] = hiC ? b1 : a1;
            pb.wd[2] = hiC ? b2 : a2;
            pb.wd[3] = hiC ? b3 : a3;
            __builtin_amdgcn_s_setprio(1);
#pragma unroll
            for (int n = 0; n < 8; n++)
                acc_o[n] = __builtin_amdgcn_mfma_f32_16x16x32_bf16(vb0[n], pb.v, acc_o[n], 0, 0, 0);
            __builtin_amdgcn_s_setprio(0);
        }
        s16x8_t vb1[8];
#pragma unroll
        for (int n = 0; n < 8; n++)
            vb1[n] = *(const s16x8_t*)&vbase[(size_t)(n * 16) * 1024 + kv0 + 32];
        {
            uint32_t a0 = __shfl((int)u[2][0], src0), b0 = __shfl((int)u[3][0], src0);
            uint32_t a1 = __shfl((int)u[2][1], src0), b1 = __shfl((int)u[3][1], src0);
            uint32_t a2 = __shfl((int)u[2][0], src1), b2 = __shfl((int)u[3][0], src1);
            uint32_t a3 = __shfl((int)u[2][1], src1), b3 = __shfl((int)u[3][1], src1);
            union { uint32_t wd[4]; s16x8_t v; } pb;
            pb.wd[0] = hiC ? b0 : a0;
            pb.wd[1] = hiC ? b1 : a1;
            pb.wd[2] = hiC ? b2 : a2;
            pb.wd[3] = hiC ? b3 : a3;
            __builtin_amdgcn_s_setprio(1);
#pragma unroll
            for (int n = 0; n < 8; n++)
                acc_o[n] = __builtin_amdgcn_mfma_f32_16x16x32_bf16(vb1[n], pb.v, acc_o[n], 0, 0, 0);
            __builtin_amdgcn_s_setprio(0);
        }

        asm volatile("s_waitcnt vmcnt(0)" ::: "memory");
        __syncthreads();
        cur ^= 1;
    }

    float inv = 1.0f / l_run;
    __hip_bfloat16* Ob = &Ks[0][0] + (size_t)w * (16 * 136);   // 16 rows x 136 (pad)
#pragma unroll
    for (int n = 0; n < 8; n++) {
        uint32_t lo = pack_bf16(acc_o[n][0] * inv, acc_o[n][1] * inv);
        uint32_t hi = pack_bf16(acc_o[n][2] * inv, acc_o[n][3] * inv);
        uint32_t* dst = (uint32_t*)&Ob[lrow * 136 + n * 16 + lkg * 4];
        dst[0] = lo;
        dst[1] = hi;
    }
    asm volatile("s_waitcnt lgkmcnt(0)" ::: "memory");
    __builtin_amdgcn_sched_barrier(0);
#pragma unroll
    for (int it = 0; it < 4; it++) {
        int tr = it * 4 + lkg;
        s16x8_t ov = *(const s16x8_t*)&Ob[tr * 136 + lrow * 8];
        *(s16x8_t*)&attn_out[(size_t)(b * 1024 + q0 + w * 16 + tr) * 4096 + h * 128 + lrow * 8] = ov;
    }
}

extern "C" void kernel_launch(void* const* d_in, const int* in_sizes, int n_in,
                              void* d_out, int out_size, void* d_ws, size_t ws_size,
                              hipStream_t stream) {
    const float* hidden = (const float*)d_in[0];
    const float* w_qa   = (const float*)d_in[1];
    const float* g_qa   = (const float*)d_in[2];
    const float* w_qb   = (const float*)d_in[3];
    const float* w_kva  = (const float*)d_in[4];
    const float* g_kva  = (const float*)d_in[5];
    const float* w_kvb  = (const float*)d_in[6];
    const float* w_o    = (const float*)d_in[7];
    float* out = (float*)d_out;

    char* base = (char*)d_ws;
    size_t off = 0;
    auto alloc = [&](size_t bytes) -> void* {
        off = (off + 255) & ~(size_t)255;
        void* p = base + off;
        off += bytes;
        return p;
    };
    float* cos_t = (float*)alloc(1024 * 64 * 4);
    float* sin_t = (float*)alloc(1024 * 64 * 4);
    __hip_bfloat16* hid_b  = (__hip_bfloat16*)alloc(2048ull * 4096 * 2);  // later reused as V_T
    // wqaT and wkvaT MUST be adjacent+contiguous: combined BT [2176][4096] for merged GEMM.
    __hip_bfloat16* wqaT   = (__hip_bfloat16*)alloc(1536ull * 4096 * 2);  // 12582912 B, 256-aligned
    __hip_bfloat16* wkvaT  = (__hip_bfloat16*)alloc(640ull * 4096 * 2);   // = wqaT + 1536*4096
    __hip_bfloat16* wqbT   = (__hip_bfloat16*)alloc(6144ull * 1536 * 2);  // later reused as attn_out
    __hip_bfloat16* wkvbT  = (__hip_bfloat16*)alloc(8192ull * 512 * 2);
    __hip_bfloat16* woT    = (__hip_bfloat16*)alloc(4096ull * 4096 * 2);
    float* q_a             = (float*)alloc(2048ull * 1536 * 4);           // K-split part 0
    __hip_bfloat16* q_c    = (__hip_bfloat16*)alloc(2048ull * 1536 * 2);
    __hip_bfloat16* q_buf  = (__hip_bfloat16*)alloc(2048ull * 6144 * 2);  // part-1 overlay until qb GEMM
    float* kv              = (float*)alloc(2048ull * 640 * 4);            // K-split part 0
    __hip_bfloat16* k_c    = (__hip_bfloat16*)alloc(2048ull * 512 * 2);
    __hip_bfloat16* k_rope = (__hip_bfloat16*)alloc(2048ull * 64 * 2);
    __hip_bfloat16* kst    = (__hip_bfloat16*)alloc(2048ull * 8192 * 2);
    __hip_bfloat16* V_T      = hid_b;   // hid_b dead after the merged first GEMM
    __hip_bfloat16* attn_out = wqbT;    // wqbT dead after q GEMM
    // K-split part-1 outputs overlaid on q_buf (q_buf not written until qb GEMM,
    // which runs after rmsnorm2/rope consume the parts): 12.6MB + 5.2MB <= 25.2MB.
    float* q_a1 = (float*)q_buf;
    float* kv1  = (float*)((char*)q_buf + 2048ull * 1536 * 4);

    const float qscale = 0.07216878364870323f;   // 192^-0.5, folded into w_qb

    rope_table_kernel<<<256, 256, 0, stream>>>(cos_t, sin_t);
    f32_to_bf16_kernel<<<8192, 256, 0, stream>>>(hidden, hid_b, 2048 * 4096 / 4);
    transpose_convert<<<dim3(1536 / 128, 4096 / 32), 256, 0, stream>>>(w_qa, wqaT, 4096, 1536, 1536, 1.0f);
    transpose_convert<<<dim3(640 / 128, 4096 / 32), 256, 0, stream>>>(w_kva, wkvaT, 4096, 576, 640, 1.0f);
    transpose_convert<<<dim3(6144 / 128, 1536 / 32), 256, 0, stream>>>(w_qb, wqbT, 1536, 6144, 6144, qscale);
    transpose_convert<<<dim3(8192 / 128, 512 / 32), 256, 0, stream>>>(w_kvb, wkvbT, 512, 8192, 8192, 1.0f);
    transpose_convert<<<dim3(4096 / 128, 4096 / 32), 256, 0, stream>>>(w_o, woT, 4096, 4096, 4096, 1.0f);

    // merged qa|kva GEMM, K-split x2: grid (17,16,2); part z covers K in [z*2048,(z+1)*2048)
    gemm_bt_128<2><<<dim3(17, 16, 2), 256, 0, stream>>>(hid_b, wqaT, q_a, kv, q_a1, kv1,
                                                        2048, 2176, 2048, 4096, 1536, 640,
                                                        nullptr, nullptr);
    rmsnorm2_kernel<<<2048, 256, 0, stream>>>(q_a, q_a1, g_qa, q_c, 1536, 1536);
    rmsnorm2_rope_kernel<<<2048, 256, 0, stream>>>(kv, kv1, g_kva, k_c, cos_t, sin_t, k_rope);
    // qb GEMM with fused rope (MODE 3) -> q_buf (overwrites the part-1 overlay, now dead)
    gemm_bt_128<3><<<dim3(6144 / 128, 16), 256, 0, stream>>>(q_c, wqbT, q_buf, nullptr, nullptr, nullptr,
                                                             2048, 6144, 1536, 1536, 0, 0, cos_t, sin_t);
    // kvb GEMM with fused V-transpose (MODE 4): nope cols -> kst, V cols -> V_T directly
    gemm_bt_128<4><<<dim3(8192 / 128, 16), 256, 0, stream>>>(k_c, wkvbT, kst, nullptr, V_T, nullptr,
                                                             2048, 8192, 512, 512, 0, 0, nullptr, nullptr);
    attn8_kernel<<<1024, 256, 0, stream>>>(q_buf, kst, k_rope, V_T, attn_out);
    gemm_bt_128<0><<<dim3(4096 / 128, 16), 256, 0, stream>>>(attn_out, woT, out, nullptr, nullptr, nullptr,
                                                             2048, 4096, 4096, 4096, 0, 0, nullptr, nullptr);
}